// Round 6
// baseline (161.069 us; speedup 1.0000x reference)
//
#include <hip/hip_runtime.h>
#include <math.h>

#define BATCH 4
#define KQ    2048
#define NPTS  4096
#define CIN   61
#define KNN   32
#define ROWS  (BATCH*KQ*KNN)   // 262144

// ---------------- ws layout (bytes) ----------------
#define OFF_IDX  0         // u16 [262144] = 524288
#define OFF_ACC  524288    // f32 [64 slots][128] = 32768 (sum 0..63 | sumsq 64..127)
#define OFF_ATTA 557056    // f32[256]
#define OFF_W1F  558080    // bf16 frag-major = 16384
#define OFF_W2F  574464    // 32768
#define OFF_W3F  607232    // 16384 (end 623616)

typedef __attribute__((ext_vector_type(8)))  short bfrag;     // 8 bf16
typedef __attribute__((ext_vector_type(4)))  unsigned ufrag;  // 8 bf16 as 4 u32
typedef __attribute__((ext_vector_type(16))) float cfrag;     // 32x32 acc

__device__ __forceinline__ unsigned short bf16_rne(float x) {
  unsigned u = __float_as_uint(x);
  unsigned r = u + 0x7fffu + ((u >> 16) & 1u);
  return (unsigned short)(r >> 16);
}
__device__ __forceinline__ float4 ld4u(const float* p) {  // 4B-aligned vec load
  float4 r; __builtin_memcpy(&r, p, 16); return r;
}
__device__ __forceinline__ unsigned cvtpk(float lo, float hi) {
  unsigned r;
  asm("v_cvt_pk_bf16_f32 %0, %1, %2" : "=v"(r) : "v"(lo), "v"(hi));
  return r;
}
__device__ __forceinline__ float up_lo(unsigned pk) { return __uint_as_float(pk << 16); }
__device__ __forceinline__ float up_hi(unsigned pk) { return __uint_as_float(pk & 0xffff0000u); }

__device__ __forceinline__ cfrag zero16() {
  cfrag z;
#pragma unroll
  for (int i = 0; i < 16; ++i) z[i] = 0.f;
  return z;
}
__device__ __forceinline__ cfrag mfma_bu(bfrag a, ufrag b, cfrag c) {
  return __builtin_amdgcn_mfma_f32_32x32x16_bf16(a, __builtin_bit_cast(bfrag, b), c, 0, 0, 0);
}
__device__ __forceinline__ cfrag mfma_ub(ufrag a, bfrag b, cfrag c) {
  return __builtin_amdgcn_mfma_f32_32x32x16_bf16(__builtin_bit_cast(bfrag, a), b, c, 0, 0, 0);
}
__device__ __forceinline__ cfrag mfma_uu(ufrag a, ufrag b, cfrag c) {
  return __builtin_amdgcn_mfma_f32_32x32x16_bf16(__builtin_bit_cast(bfrag, a), __builtin_bit_cast(bfrag, b), c, 0, 0, 0);
}

// tight per-wave bound (32nd of 64 minima-of-64 over ALL points) =>
// E[cand] ~ 4096*ln2/64 ~ 44, sigma ~ 6.6 -> 128 is a >12-sigma cap.
#define NCAND 128

// exact select of KNN smallest among mcount candidates (NS = ceil(mcount/64)).
// Called by the owning wave only; no cross-wave state.
template<int NS>
__device__ __forceinline__ void select_emit(
    const unsigned* __restrict__ VAL, const unsigned short* __restrict__ IDXL,
    int mcount, unsigned hib, unsigned lob, int lane,
    const float* __restrict__ Pb, float kx, float ky, float kz,
    unsigned short* __restrict__ dst, int* __restrict__ SEL,
    float* __restrict__ accs) {
  const unsigned long long lmask = (1ull << lane) - 1ull;
  unsigned e[NS];
#pragma unroll
  for (int s = 0; s < NS; ++s) {
    int ei = s*64 + lane;
    e[s] = (ei < mcount) ? VAL[ei] : 0xffffffffu;
  }
  unsigned lo2 = lob, hi2 = hib;   // invariant: count(<= hi2) >= KNN
  while (lo2 < hi2) {
    unsigned mid = lo2 + ((hi2 - lo2) >> 1);
    int c = 0;
#pragma unroll
    for (int s = 0; s < NS; ++s) c += (int)__popcll(__ballot(e[s] <= mid));
    if (c == KNN) { hi2 = mid; break; }   // exact set found
    if (c > KNN) hi2 = mid; else lo2 = mid + 1;
  }
  const unsigned T = hi2;
  float r0=0.f,r1=0.f,r2=0.f,r3=0.f,r4=0.f,r5=0.f;
  int base2 = 0;
#pragma unroll
  for (int s = 0; s < NS; ++s) {
    bool p = (e[s] <= T);
    unsigned long long m = __ballot(p);
    if (p) {
      int pos = base2 + (int)__popcll(m & lmask);
      if (pos < KNN) {
        int n = (int)IDXL[s*64 + lane];
        SEL[pos] = n;
        dst[pos] = (unsigned short)n;
        float dx = Pb[n*3+0]-kx, dy = Pb[n*3+1]-ky, dz = Pb[n*3+2]-kz;
        r0 += dx; r1 += dy; r2 += dz;
        r3 += dx*dx; r4 += dy*dy; r5 += dz*dz;
      }
    }
    base2 += (int)__popcll(m);
  }
#pragma unroll
  for (int off = 32; off > 0; off >>= 1) {
    r0 += __shfl_down(r0, off); r1 += __shfl_down(r1, off);
    r2 += __shfl_down(r2, off); r3 += __shfl_down(r3, off);
    r4 += __shfl_down(r4, off); r5 += __shfl_down(r5, off);
  }
  if (lane == 0) {
    atomicAdd(&accs[0], r0); atomicAdd(&accs[1], r1); atomicAdd(&accs[2], r2);
    atomicAdd(&accs[64], r3); atomicAdd(&accs[65], r4); atomicAdd(&accs[66], r5);
  }
}

// ====== topk: FOUR queries per block, wave w owns query w END-TO-END ======
// (distances over ALL 4096 points per wave, interleaved idx = j*64+lane,
//  no cross-wave barriers until the BN merge). Prep work folded into
//  blocks 0..128 as an epilogue.
// W2/W3 staged with pi-permuted K so that C-layout -> operand-frag conversion
// in main_kernel is in-lane: k_orig = 32*(kc>>1)+16*(kc&1)+4*h+(j&3)+8*(j>>2).
// W3 staged TRANSPOSED (as B operand: col = out-channel o).
__global__ __launch_bounds__(256, 4) void topk_kernel(
    const float* __restrict__ keys, const float* __restrict__ points,
    const float* __restrict__ feats,
    const float* __restrict__ w1, const float* __restrict__ w2,
    const float* __restrict__ w3,
    const float* __restrict__ att_w, const float* __restrict__ att_q,
    unsigned short* __restrict__ idx_out, float* __restrict__ acc,
    short* __restrict__ w1f, short* __restrict__ w2f, short* __restrict__ w3f,
    float* __restrict__ attA) {
  __shared__ unsigned VAL[4][NCAND];
  __shared__ unsigned short IDXL[4][NCAND];
  __shared__ int SEL[4][KNN];
  __shared__ float FRED[64*33];   // merged 4-query partials, stride-33
  __shared__ float FQ[64*33];
  const int tid = threadIdx.x;
  const int lane = tid & 63, wid = tid >> 6;
  const int g0 = blockIdx.x * 4;
  const int b = g0 >> 11;
  // this wave's query (wave-uniform -> scalar regs)
  const int gq = __builtin_amdgcn_readfirstlane(g0 + wid);
  const float kx = keys[(size_t)gq*3+0];
  const float ky = keys[(size_t)gq*3+1];
  const float kz = keys[(size_t)gq*3+2];
  const float* __restrict__ Pb = points + (size_t)b * NPTS * 3;

  // ---- distances for own query over ALL points: idx = j*64 + lane ----
  // (per-j loads are wave-contiguous 768B windows -> well coalesced)
  unsigned u[64];
  unsigned lmin = 0xffffffffu;
#pragma unroll
  for (int jb = 0; jb < 8; ++jb) {
    float4 t[8];
#pragma unroll
    for (int q = 0; q < 8; ++q) {
      const int idx = (jb*8 + q)*64 + lane;
      if (jb == 7 && q == 7) {
        // last point: read at idx*3-1 and use .yzw (stays in-bounds)
        float4 tt = ld4u(Pb + (size_t)idx*3 - 1);
        t[q].x = tt.y; t[q].y = tt.z; t[q].z = tt.w; t[q].w = 0.f;
      } else {
        t[q] = ld4u(Pb + (size_t)idx*3);
      }
    }
#pragma unroll
    for (int q = 0; q < 8; ++q) {
      float dx = t[q].x - kx, dy = t[q].y - ky, dz = t[q].z - kz;
      unsigned d = __float_as_uint(dx*dx + dy*dy + dz*dz);
      u[jb*8 + q] = d;
      lmin = min(lmin, d);
    }
  }

  // ---- per-wave bound: [min,max] of lane-mins, bsearch w/ early exit ----
  unsigned wlo = lmin, whi = lmin;
#pragma unroll
  for (int off = 1; off < 64; off <<= 1) {
    unsigned a0 = (unsigned)__shfl_xor((int)wlo, off);
    unsigned a1 = (unsigned)__shfl_xor((int)whi, off);
    wlo = min(wlo, a0); whi = max(whi, a1);
  }
  unsigned hib;
  {
    unsigned lo = wlo, hi = whi;
    while (lo < hi) {
      unsigned mid = lo + ((hi - lo) >> 1);
      int c = (int)__popcll(__ballot(lmin <= mid));
      if (c == KNN) { hi = mid; break; }
      if (c > KNN) hi = mid; else lo = mid + 1;
    }
    hib = hi;
  }

  // ---- wave-local count + exclusive scan + compaction ----
  int cnt = 0;
#pragma unroll
  for (int j = 0; j < 64; ++j) cnt += (u[j] <= hib) ? 1 : 0;
  int inc = cnt;
#pragma unroll
  for (int off = 1; off < 64; off <<= 1) {
    int t = __shfl_up(inc, off);
    if (lane >= off) inc += t;
  }
  const int mtot = __shfl(inc, 63);
  {
    int p = inc - cnt;
#pragma unroll
    for (int j = 0; j < 64; ++j) {
      if (u[j] <= hib) {
        if (p < NCAND) {
          VAL[wid][p] = u[j];
          IDXL[wid][p] = (unsigned short)(j*64 + lane);
        }
        ++p;
      }
    }
  }
  const int mcount = min(mtot, NCAND);

  // ---- exact select for own query (VAL written by this wave only) ----
  float* accs = &acc[(blockIdx.x & 63)*128];
  if (mcount <= 64)
    select_emit<1>(VAL[wid], IDXL[wid], mcount, hib, wlo, lane, Pb,
                   kx, ky, kz, idx_out + (size_t)gq*KNN, SEL[wid], accs);
  else
    select_emit<2>(VAL[wid], IDXL[wid], mcount, hib, wlo, lane, Pb,
                   kx, ky, kz, idx_out + (size_t)gq*KNN, SEL[wid], accs);
  __syncthreads();   // S4: all SEL ready

  // feats BN stats merged over 4 queries: rowslot=tid>>3 (32), chunk=tid&7
  {
    const int row = tid >> 3, chunk = tid & 7;
    const int nA = SEL[0][row], nB = SEL[1][row];
    const int nC = SEL[2][row], nD = SEL[3][row];
    const float* frA = feats + ((size_t)b*NPTS + nA)*CIN;
    const float* frB = feats + ((size_t)b*NPTS + nB)*CIN;
    const float* frC = feats + ((size_t)b*NPTS + nC)*CIN;
    const float* frD = feats + ((size_t)b*NPTS + nD)*CIN;
    float fs[8] = {0,0,0,0,0,0,0,0}, fq[8] = {0,0,0,0,0,0,0,0};
    if (chunk < 7) {
      const float* fr[4] = {frA, frB, frC, frD};
#pragma unroll
      for (int qq = 0; qq < 4; ++qq) {
        float4 a0 = ld4u(fr[qq] + chunk*8), a1 = ld4u(fr[qq] + chunk*8 + 4);
        fs[0]+=a0.x; fq[0]+=a0.x*a0.x; fs[1]+=a0.y; fq[1]+=a0.y*a0.y;
        fs[2]+=a0.z; fq[2]+=a0.z*a0.z; fs[3]+=a0.w; fq[3]+=a0.w*a0.w;
        fs[4]+=a1.x; fq[4]+=a1.x*a1.x; fs[5]+=a1.y; fq[5]+=a1.y*a1.y;
        fs[6]+=a1.z; fq[6]+=a1.z*a1.z; fs[7]+=a1.w; fq[7]+=a1.w*a1.w;
      }
    } else {
#pragma unroll
      for (int i = 0; i < 5; ++i) {
        float va = frA[56+i], vb = frB[56+i], vc = frC[56+i], vd = frD[56+i];
        fs[i] = va + vb + vc + vd;
        fq[i] = va*va + vb*vb + vc*vc + vd*vd;
      }
    }
#pragma unroll
    for (int i = 0; i < 8; ++i) {
      FRED[(chunk*8 + i)*33 + row] = fs[i];
      FQ  [(chunk*8 + i)*33 + row] = fq[i];
    }
  }
  __syncthreads();   // S5
  if (tid < 64) {
    float s = 0.f, q2 = 0.f;
#pragma unroll
    for (int r = 0; r < 32; ++r) {
      s  += FRED[tid*33 + r];
      q2 += FQ[tid*33 + r];
    }
    if (tid < CIN) {
      atomicAdd(&accs[3 + tid], s);
      atomicAdd(&accs[64 + 3 + tid], q2);
    }
  }

  // ---- folded prep epilogue: blocks 0..127 convert weights (1 short per
  // thread), block 128 computes attA. No separate tail dispatch. ----
  if (blockIdx.x < 128) {
    const int t = blockIdx.x * 256 + tid;   // 32768 total
    if (t < 8192) {            // W1 (A role): NH=128, K=64 natural, KC=4
      int j = t & 7, ln = (t >> 3) & 63, tk = t >> 9;
      int kc = tk & 3, tile = tk >> 2;
      int nh = tile*32 + (ln & 31), k = kc*16 + (ln >> 5)*8 + j;
      w1f[t] = (short)bf16_rne(w1[k*128 + nh]);
    } else if (t < 24576) {    // W2 (A role): NH=128, K=128 pi-permuted, KC=8
      int t2 = t - 8192;
      int j = t2 & 7, ln = (t2 >> 3) & 63, tk = t2 >> 9;
      int kc = tk & 7, tile = tk >> 3;
      int nh = tile*32 + (ln & 31);
      int k = 32*(kc>>1) + 16*(kc&1) + 4*(ln>>5) + (j&3) + 8*(j>>2);
      w2f[t2] = (short)bf16_rne(w2[k*128 + nh]);
    } else {                   // W3^T (B role): col=o (64), K=128 pi-permuted, KC=8
      int t3 = t - 24576;
      int j = t3 & 7, ln = (t3 >> 3) & 63, tk = t3 >> 9;
      int kc = tk & 7, tile = tk >> 3;
      int nh = tile*32 + (ln & 31);
      int k = 32*(kc>>1) + 16*(kc&1) + 4*(ln>>5) + (j&3) + 8*(j>>2);
      w3f[t3] = (short)bf16_rne(w3[k*64 + nh]);
    }
  } else if (blockIdx.x == 128) {   // attA[c][h] = sum_d att_w[c,h*64+d]*att_q[h,d]
    const int t = tid, c = t >> 2, hh = t & 3;
    float s = 0.f;
    for (int d = 0; d < 64; ++d) s += att_w[c*256 + hh*64 + d] * att_q[hh*64 + d];
    attA[c*4 + hh] = s;
  }
}

// ---------------- main-kernel LDS offsets (bytes) ----------------
#define L_W1F 0        // 16384
#define L_W2F 16384    // 32768
#define L_W3F 49152    // 16384
#define L_SH  65536    // SAe hi frags: 4 kc * 64 * 8 shorts = 4096
#define L_SL  69632    // SAe lo frags: 4096
#define L_B1  73728    // 512
#define L_B2  74240    // 512
#define L_B3  74752    // 256
#define L_WSC 75008    // 8 waves * 512 B w-scratch (phase0: TMP [8][128] f32)
#define L_SC  79104    // f32[64]
#define L_TOT 79360    // < 80 KiB -> 2 blocks/CU

// ====== main: one wave per query, ZERO in-loop barriers ======
// chain: gather(regs) -> E-MFMA(hi/lo) -> in-reg softmax -> w bounce (512B
// per-wave LDS, intra-wave) -> G1 -> G2 -> G3(transposed) -> out-MFMA(hi/lo).
// All C->operand re-frags are in-lane cvt_pk thanks to pi-permuted weights.
// q0's gather is hoisted BEFORE phase0 (hides scatter latency under staging).
__global__ __launch_bounds__(512, 4) void main_kernel(
    const float* __restrict__ keys, const float* __restrict__ points,
    const float* __restrict__ feats, const unsigned short* __restrict__ idxg,
    const short* __restrict__ w1f, const short* __restrict__ w2f,
    const short* __restrict__ w3f,
    const float* __restrict__ b1, const float* __restrict__ b2,
    const float* __restrict__ b3,
    const float* __restrict__ attAg, const float* __restrict__ accg,
    const float* __restrict__ gammav, float* __restrict__ out) {
  __shared__ __align__(16) char smem[L_TOT];
  const int tid = threadIdx.x;
  const int bid = blockIdx.x;
  const int wid = tid >> 6, lane = tid & 63;
  const int col = lane & 31, h = lane >> 5;

  float* WS = (float*)(smem + L_WSC) + wid*128;   // per-wave [32][4]
  const short* SW1 = (const short*)(smem + L_W1F);
  const short* SW2 = (const short*)(smem + L_W2F);
  const short* SW3 = (const short*)(smem + L_W3F);
  const float* SB1 = (const float*)(smem + L_B1);
  const float* SB2 = (const float*)(smem + L_B2);

  // ---- gather + pack (hi + residual lo) for one query ----
  auto gather_pack = [&](int g, int n, ufrag* ahi, ufrag* alo) {
    const int b = g >> 11;
    const float* frow = feats + ((size_t)b*NPTS + n)*CIN;
    float v[4][8];
    if (h == 0) {
      const float* Pb = points + (size_t)b*NPTS*3;
      v[0][0] = Pb[n*3+0] - keys[(size_t)g*3+0];
      v[0][1] = Pb[n*3+1] - keys[(size_t)g*3+1];
      v[0][2] = Pb[n*3+2] - keys[(size_t)g*3+2];
      float4 t0 = ld4u(frow);
      v[0][3]=t0.x; v[0][4]=t0.y; v[0][5]=t0.z; v[0][6]=t0.w;
      v[0][7] = frow[4];
    } else {
      float4 a0 = ld4u(frow+5), a1 = ld4u(frow+9);
      v[0][0]=a0.x; v[0][1]=a0.y; v[0][2]=a0.z; v[0][3]=a0.w;
      v[0][4]=a1.x; v[0][5]=a1.y; v[0][6]=a1.z; v[0][7]=a1.w;
    }
#pragma unroll
    for (int kc = 1; kc < 4; ++kc) {
      const int f0 = kc*16 + 8*h - 3;
      float4 a0 = ld4u(frow+f0), a1 = ld4u(frow+f0+4);
      v[kc][0]=a0.x; v[kc][1]=a0.y; v[kc][2]=a0.z; v[kc][3]=a0.w;
      v[kc][4]=a1.x; v[kc][5]=a1.y; v[kc][6]=a1.z; v[kc][7]=a1.w;
    }
#pragma unroll
    for (int kc = 0; kc < 4; ++kc)
#pragma unroll
      for (int p = 0; p < 4; ++p) {
        unsigned pk = cvtpk(v[kc][2*p], v[kc][2*p+1]);
        ahi[kc][p] = pk;
        alo[kc][p] = cvtpk(v[kc][2*p] - up_lo(pk), v[kc][2*p+1] - up_hi(pk));
      }
  };

  // ---- full per-query chain (E -> softmax -> bounce -> G1 -> G2 -> G3+out) --
  auto chain = [&](int g, const ufrag* ahi, const ufrag* alo) {
    // E: logits [n x hd], hi/lo split (~f32 accurate)
    cfrag Ef = zero16();
#pragma unroll
    for (int kc = 0; kc < 4; ++kc) {
      bfrag sh = *(const bfrag*)((const short*)(smem + L_SH) + (kc*64 + lane)*8);
      bfrag sl = *(const bfrag*)((const short*)(smem + L_SL) + (kc*64 + lane)*8);
      Ef = mfma_ub(ahi[kc], sh, Ef);
      Ef = mfma_ub(alo[kc], sh, Ef);
      Ef = mfma_ub(ahi[kc], sl, Ef);
    }

    // softmax over n (16 regs in-lane + one xor-32)
    float mx = Ef[0];
#pragma unroll
    for (int i = 1; i < 16; ++i) mx = fmaxf(mx, Ef[i]);
    mx = fmaxf(mx, __shfl_xor(mx, 32));
    float wsm[16], ssum = 0.f;
#pragma unroll
    for (int i = 0; i < 16; ++i) { wsm[i] = __expf(Ef[i] - mx); ssum += wsm[i]; }
    ssum += __shfl_xor(ssum, 32);
    const float invs = 1.f / ssum;
#pragma unroll
    for (int i = 0; i < 16; ++i) wsm[i] *= invs;

    // bounce w through per-wave LDS (no barrier: intra-wave)
    if (col < 4) {
#pragma unroll
      for (int i = 0; i < 8; ++i) {
        const int c0 = (2*i & 3) + 8*(i >> 1);   // 0,2,8,10,16,18,24,26
        const int nA = c0 + 4*h;
        WS[nA*4 + col]     = wsm[2*i];
        WS[nA*4 + 4 + col] = wsm[2*i+1];
      }
    }
    const int hdc = col & 3;
    ufrag whi[2], wlo[2];
#pragma unroll
    for (int bb = 0; bb < 2; ++bb)
#pragma unroll
      for (int p = 0; p < 4; ++p) {
        const int c0 = (2*p & 3) + 8*(p >> 1);
        const int n0 = 16*bb + 4*h + c0;
        float r0 = WS[n0*4 + hdc], r1 = WS[n0*4 + 4 + hdc];
        unsigned pk = cvtpk(r0, r1);
        whi[bb][p] = pk;
        wlo[bb][p] = cvtpk(r0 - up_lo(pk), r1 - up_hi(pk));
      }

    // GEMM1: 64 -> 128, relu, in-lane re-frag to A2
    ufrag a2[8];
#pragma unroll
    for (int t = 0; t < 4; ++t) {
      cfrag acc = zero16();
#pragma unroll
      for (int kc = 0; kc < 4; ++kc) {
        bfrag wf = *(const bfrag*)(SW1 + ((t*4 + kc)*64 + lane)*8);
        acc = mfma_bu(wf, ahi[kc], acc);
      }
#pragma unroll
      for (int i = 0; i < 8; ++i) {
        const int c0 = (2*i & 3) + 8*(i >> 1);
        float2 bb2 = *(const float2*)(SB1 + t*32 + c0 + 4*h);
        float x0 = fmaxf(acc[2*i]   + bb2.x, 0.f);
        float x1 = fmaxf(acc[2*i+1] + bb2.y, 0.f);
        a2[2*t + (i>>2)][i&3] = cvtpk(x0, x1);
      }
    }

    // GEMM2: 128 -> 128, relu, re-frag to A3
    ufrag a3[8];
#pragma unroll
    for (int t = 0; t < 4; ++t) {
      cfrag acc = zero16();
#pragma unroll
      for (int kc = 0; kc < 8; ++kc) {
        bfrag wf = *(const bfrag*)(SW2 + ((t*8 + kc)*64 + lane)*8);
        acc = mfma_bu(wf, a2[kc], acc);
      }
#pragma unroll
      for (int i = 0; i < 8; ++i) {
        const int c0 = (2*i & 3) + 8*(i >> 1);
        float2 bb2 = *(const float2*)(SB2 + t*32 + c0 + 4*h);
        float x0 = fmaxf(acc[2*i]   + bb2.x, 0.f);
        float x1 = fmaxf(acc[2*i+1] + bb2.y, 0.f);
        a3[2*t + (i>>2)][i&3] = cvtpk(x0, x1);
      }
    }

    // GEMM3 (transposed: D3'[n][o] = act2^T * W3^T) + out-MFMA
#pragma unroll
    for (int t = 0; t < 2; ++t) {
      cfrag acc = zero16();
#pragma unroll
      for (int kc = 0; kc < 8; ++kc) {
        bfrag wf = *(const bfrag*)(SW3 + ((t*8 + kc)*64 + lane)*8);
        acc = mfma_ub(a3[kc], wf, acc);
      }
      const float bz = ((const float*)(smem + L_B3))[t*32 + col];
#pragma unroll
      for (int i = 0; i < 16; ++i) acc[i] += bz;
      // lat^T re-frag (hi + lo)
      ufrag lh[2], ll[2];
#pragma unroll
      for (int i = 0; i < 8; ++i) {
        unsigned pk = cvtpk(acc[2*i], acc[2*i+1]);
        lh[i>>2][i&3] = pk;
        ll[i>>2][i&3] = cvtpk(acc[2*i] - up_lo(pk), acc[2*i+1] - up_hi(pk));
      }
      cfrag og = zero16();
#pragma unroll
      for (int bb = 0; bb < 2; ++bb) og = mfma_uu(lh[bb], whi[bb], og);
#pragma unroll
      for (int bb = 0; bb < 2; ++bb) og = mfma_uu(ll[bb], whi[bb], og);
#pragma unroll
      for (int bb = 0; bb < 2; ++bb) og = mfma_uu(lh[bb], wlo[bb], og);
      if (col < 4) {
        float* op = out + (size_t)g*256 + t*128 + col;
#pragma unroll
        for (int i = 0; i < 16; ++i) {
          const int orow = (i&3) + 8*(i>>2) + 4*h;
          op[orow*4] = og[i];
        }
      }
    }
  };

  // ---- hoisted q0 gather (+ q1 idx prefetch): hides under phase0 staging ----
  const int g0q = bid*8 + wid;
  const int g1q = g0q + 4096;
  const int n0 = (int)idxg[(size_t)g0q*KNN + col];
  const int n1 = (int)idxg[(size_t)g1q*KNN + col];
  ufrag ahi0[4], alo0[4];
  gather_pack(g0q, n0, ahi0, alo0);

  // ---- phase 0: stage weights + compute Ae = gamma*invstd*attA ----
  {
    // weight frags: w1f|w2f|w3f contiguous in ws = 65536 B = 4096 uint4
    const uint4* src = (const uint4*)w1f;
    uint4* dst = (uint4*)smem;
#pragma unroll
    for (int r = 0; r < 8; ++r) dst[r*512 + tid] = src[r*512 + tid];
    if (tid < 128) ((float*)(smem + L_B1))[tid] = b1[tid];
    else if (tid < 256) ((float*)(smem + L_B2))[tid-128] = b2[tid-128];
    else if (tid < 320) ((float*)(smem + L_B3))[tid-256] = b3[tid-256];
    // BN stats reduce
    float* TMP = (float*)(smem + L_WSC);    // [8][128]
    {
      int c = tid & 63, p = tid >> 6;
      float s = 0.f, s2 = 0.f;
      for (int k = p; k < 64; k += 8) {
        s += accg[k*128 + c]; s2 += accg[k*128 + 64 + c];
      }
      TMP[p*128 + c] = s; TMP[p*128 + 64 + c] = s2;
    }
    __syncthreads();
    float* SCp = (float*)(smem + L_SC);
    if (tid < 64) {
      float s = 0.f, s2 = 0.f;
#pragma unroll
      for (int p = 0; p < 8; ++p) { s += TMP[p*128 + tid]; s2 += TMP[p*128 + 64 + tid]; }
      const float invR = 1.f / (float)ROWS;
      float mean = s * invR;
      float var = s2 * invR - mean * mean;
      SCp[tid] = gammav[tid] * rsqrtf(var + 1e-5f);
    }
    __syncthreads();
    // SAe hi/lo frags (B role: col=hd (<4 valid), k natural pi1)
    {
      const int s = tid >> 8;           // 0 = hi, 1 = lo
      const int kc = (tid >> 6) & 3;
      const int ln = tid & 63;
      const int hd = ln & 31;
      short* dstf = (short*)(smem + (s ? L_SL : L_SH)) + (kc*64 + ln)*8;
#pragma unroll
      for (int j = 0; j < 8; ++j) {
        const int ch = kc*16 + (ln>>5)*8 + j;
        float val = (hd < 4) ? attAg[ch*4 + hd] * SCp[ch] : 0.f;
        unsigned hb = bf16_rne(val);
        if (s) {
          float lo = val - __uint_as_float(hb << 16);
          dstf[j] = (short)bf16_rne(lo);
        } else {
          dstf[j] = (short)hb;
        }
      }
    }
    __syncthreads();
  }

  // ---- q0 (gather already in registers) ----
  chain(g0q, ahi0, alo0);

  // ---- q1 (idx prefetched; gather now) ----
  ufrag ahi1[4], alo1[4];
  gather_pack(g1q, n1, ahi1, alo1);
  chain(g1q, ahi1, alo1);
}

extern "C" void kernel_launch(void* const* d_in, const int* in_sizes, int n_in,
                              void* d_out, int out_size, void* d_ws, size_t ws_size,
                              hipStream_t stream) {
  const float* keys   = (const float*)d_in[0];
  const float* points = (const float*)d_in[1];
  const float* feats  = (const float*)d_in[2];
  const float* nx_w1  = (const float*)d_in[3];
  const float* nx_b1  = (const float*)d_in[4];
  const float* nx_w2  = (const float*)d_in[5];
  const float* nx_b2  = (const float*)d_in[6];
  const float* nx_w3  = (const float*)d_in[7];
  const float* nx_b3  = (const float*)d_in[8];
  // sx_w*/sx_b* (9..14), att_b (16), bn_beta (19): n-constant in softmax -> dead
  const float* att_w  = (const float*)d_in[15];
  const float* att_q  = (const float*)d_in[17];
  const float* gamma  = (const float*)d_in[18];
  float* out = (float*)d_out;

  char* ws = (char*)d_ws;
  unsigned short* idxp = (unsigned short*)(ws + OFF_IDX);
  float* acc  = (float*)(ws + OFF_ACC);
  float* attA = (float*)(ws + OFF_ATTA);
  short* w1f  = (short*)(ws + OFF_W1F);
  short* w2f  = (short*)(ws + OFF_W2F);
  short* w3f  = (short*)(ws + OFF_W3F);

  hipMemsetAsync(acc, 0, 32768, stream);
  topk_kernel<<<2048, 256, 0, stream>>>(keys, points, feats,
      nx_w1, nx_w2, nx_w3, att_w, att_q, idxp, acc, w1f, w2f, w3f, attA);
  main_kernel<<<512, 512, 0, stream>>>(keys, points, feats, idxp,
      w1f, w2f, w3f, nx_b1, nx_b2, nx_b3, attA, acc, gamma, out);
}